// Round 4
// baseline (926.767 us; speedup 1.0000x reference)
//
#include <hip/hip_runtime.h>
#include <hip/hip_bf16.h>

// Problem constants (B=2,S=2048,H=1024,E=8,I=2048,topk=2)
#define T_TOKENS 4096
#define H_DIM    1024
#define E_EXP    8
#define I_DIM    2048

typedef short bf16x8 __attribute__((ext_vector_type(8)));
typedef float f32x4  __attribute__((ext_vector_type(4)));

// XOR swizzle of 16B k-group slots vs LDS row (row stride 64B)
#define SWZ(r) (((r) >> 1) & 3)

__device__ inline unsigned short f2bf(float f) {
  union { __hip_bfloat16 h; unsigned short u; } c;
  c.h = __float2bfloat16(f);
  return c.u;
}
__device__ inline float bf2f(unsigned short u) {
  union { unsigned int i; float f; } c;
  c.i = (unsigned int)u << 16;
  return c.f;
}

// async global->LDS DMA, 16 B/lane, dest = wave-uniform base + lane*16
__device__ inline void load16_lds(const void* g, void* l) {
  __builtin_amdgcn_global_load_lds(
      (const __attribute__((address_space(1))) unsigned int*)g,
      (__attribute__((address_space(3))) unsigned int*)l, 16, 0, 0);
}

// ---- cast + transpose: [E][K][N] f32 -> [E][N][K] bf16 ----
__global__ void cast_transpose_kernel(const float* __restrict__ in,
                                      unsigned short* __restrict__ out,
                                      int K, int N) {
  __shared__ float tile[64][33];
  const float* src = in + (size_t)blockIdx.z * K * N;
  unsigned short* dst = out + (size_t)blockIdx.z * K * N;
  int n0 = blockIdx.x * 32, k0 = blockIdx.y * 64;
  int tid = threadIdx.x;
#pragma unroll
  for (int r = 0; r < 8; r++) {
    int idx = r * 256 + tid;
    int kk = idx >> 5, nn = idx & 31;
    tile[kk][nn] = src[(size_t)(k0 + kk) * N + n0 + nn];
  }
  __syncthreads();
  int n = tid >> 3, kg = tid & 7;
  __align__(16) unsigned short o[8];
#pragma unroll
  for (int j = 0; j < 8; j++) o[j] = f2bf(tile[kg * 8 + j][n]);
  *(uint4*)&dst[(size_t)(n0 + n) * K + k0 + kg * 8] = *(uint4*)o;
}

// ---- router (fused x->bf16 cast): fp32 logits, top-2 softmax, lists + codes ----
__global__ void router_kernel(const float* __restrict__ x, const float* __restrict__ Wg,
                              unsigned short* __restrict__ xb,
                              int* __restrict__ counts, int* __restrict__ list_tok,
                              float* __restrict__ list_gate, int* __restrict__ tok_codes) {
  int t = blockIdx.x;
  int lane = threadIdx.x;
  float acc[8];
#pragma unroll
  for (int e = 0; e < 8; e++) acc[e] = 0.f;
  const float* xr = x + (size_t)t * H_DIM;
  unsigned short* xbr = xb + (size_t)t * H_DIM;
  for (int h = lane; h < H_DIM; h += 64) {
    float xv = xr[h];
    xbr[h] = f2bf(xv);
    const float4* w = (const float4*)(Wg + (size_t)h * 8);
    float4 w0 = w[0], w1 = w[1];
    acc[0] += xv * w0.x; acc[1] += xv * w0.y; acc[2] += xv * w0.z; acc[3] += xv * w0.w;
    acc[4] += xv * w1.x; acc[5] += xv * w1.y; acc[6] += xv * w1.z; acc[7] += xv * w1.w;
  }
#pragma unroll
  for (int off = 32; off > 0; off >>= 1)
#pragma unroll
    for (int e = 0; e < 8; e++) acc[e] += __shfl_xor(acc[e], off, 64);
  if (lane == 0) {
    int e1 = 0; float l1 = acc[0];
    for (int e = 1; e < 8; e++) if (acc[e] > l1) { l1 = acc[e]; e1 = e; }
    int e2 = -1; float l2 = -1e30f;
    for (int e = 0; e < 8; e++) if (e != e1 && acc[e] > l2) { l2 = acc[e]; e2 = e; }
    float g1 = 1.f / (1.f + expf(l2 - l1));
    float g2 = 1.f - g1;
    int p1 = atomicAdd(&counts[e1], 1);
    list_tok[e1 * T_TOKENS + p1] = t; list_gate[e1 * T_TOKENS + p1] = g1;
    int p2 = atomicAdd(&counts[e2], 1);
    list_tok[e2 * T_TOKENS + p2] = t; list_gate[e2 * T_TOKENS + p2] = g2;
    tok_codes[2 * t]     = e1 * T_TOKENS + p1;
    tok_codes[2 * t + 1] = e2 * T_TOKENS + p2;
  }
}

__global__ void prefix_kernel(const int* __restrict__ counts, int* __restrict__ base) {
  if (threadIdx.x == 0) {
    int s = 0;
    for (int e = 0; e < 8; e++) { base[e] = s; s += counts[e]; }
  }
}

// ---- GEMM1: 128 tokens x 64 i-cols (g/u interleaved B-tile), double-buffered
//      LDS, ONE barrier per K-iter, DMA(k+1) overlaps compute(k).
//      Fused silu(g)*u -> a_buf bf16 ----
__global__ __launch_bounds__(256) void gemm1_kernel(
    const unsigned short* __restrict__ xb,      // [T][1024] bf16
    const unsigned short* __restrict__ w_in_t,  // [E][4096][1024] bf16
    const int* __restrict__ counts, const int* __restrict__ base,
    const int* __restrict__ list_tok,
    unsigned short* __restrict__ a_buf)         // [8192][2048] bf16
{
  int e = blockIdx.z;
  int Ne = counts[e];
  int row0 = blockIdx.x * 128;                  // x = row-block (consecutive blocks share B)
  if (row0 >= Ne) return;
  int ib = blockIdx.y * 64;                     // i-col base
  const unsigned short* W = w_in_t + (size_t)e * 4096 * 1024;
  int slot_base = base[e];

  __shared__ __align__(16) unsigned short As[2][128 * 32];   // 2 x 8 KB
  __shared__ __align__(16) unsigned short Bs[2][128 * 32];   // 2 x 8 KB
  __shared__ int toks[128];

  int tid = threadIdx.x;
  if (tid < 128) {
    int pos = row0 + tid;
    toks[tid] = list_tok[e * T_TOKENS + (pos < Ne ? pos : 0)];
  }
  __syncthreads();

  int wv = tid >> 6, lane = tid & 63;

  // staging: wave wv stages A/B rows [32wv,32wv+32) as 2 DMAs of 16 rows each.
  const unsigned short* srcA[2];
  const unsigned short* srcB[2];
  int ldsOff[2];
#pragma unroll
  for (int d = 0; d < 2; d++) {
    int r = 32 * wv + 16 * d + (lane >> 2);        // tile-local row 0..127
    int kg = (lane & 3) ^ SWZ(r);
    srcA[d] = xb + (size_t)toks[r] * H_DIM + kg * 8;
    // B-tile row r -> W row: c=r>>6 (wave col-half), q=(r>>4)&3 (g/u alt), rr=r&15
    int c = r >> 6, q = (r >> 4) & 3, rr = r & 15;
    int wrow = (q & 1) * 2048 + ib + 32 * c + (q >> 1) * 16 + rr;
    srcB[d] = W + (size_t)wrow * H_DIM + kg * 8;
    ldsOff[d] = (32 * wv + 16 * d) * 32;
  }

  int rh = wv >> 1, ch = wv & 1;
  int l15 = lane & 15, quad = lane >> 4;

  f32x4 acc[4][4] = {};

  // prologue: stage k0=0 into buffer 0
  load16_lds(srcA[0], &As[0][ldsOff[0]]);
  load16_lds(srcA[1], &As[0][ldsOff[1]]);
  load16_lds(srcB[0], &Bs[0][ldsOff[0]]);
  load16_lds(srcB[1], &Bs[0][ldsOff[1]]);
  __syncthreads();

  int p = 0;
  for (int k0 = 0; k0 < H_DIM; k0 += 32) {
    int kn = k0 + 32;
    if (kn < H_DIM) {                           // stage next while computing current
      load16_lds(srcA[0] + kn, &As[1 - p][ldsOff[0]]);
      load16_lds(srcA[1] + kn, &As[1 - p][ldsOff[1]]);
      load16_lds(srcB[0] + kn, &Bs[1 - p][ldsOff[0]]);
      load16_lds(srcB[1] + kn, &Bs[1 - p][ldsOff[1]]);
    }
    bf16x8 af[4], bf[4];
#pragma unroll
    for (int rb = 0; rb < 4; rb++) {
      int row = rh * 64 + rb * 16 + l15;
      int kg = quad ^ SWZ(row);
      af[rb] = *(const bf16x8*)&As[p][row * 32 + kg * 8];
    }
#pragma unroll
    for (int cb = 0; cb < 4; cb++) {
      int brow = ch * 64 + cb * 16 + l15;
      int kg = quad ^ SWZ(brow);
      bf[cb] = *(const bf16x8*)&Bs[p][brow * 32 + kg * 8];
    }
#pragma unroll
    for (int rb = 0; rb < 4; rb++)
#pragma unroll
      for (int cb = 0; cb < 4; cb++)
        acc[rb][cb] = __builtin_amdgcn_mfma_f32_16x16x32_bf16(af[rb], bf[cb], acc[rb][cb], 0, 0, 0);
    __syncthreads();   // waves done reading buf p; DMA(k+1) drained (vmcnt0)
    p ^= 1;
  }

  // epilogue: B col-blocks alternate g,u,g,u (16-wide). Pair (2cp, 2cp+1).
#pragma unroll
  for (int rb = 0; rb < 4; rb++)
#pragma unroll
    for (int cp = 0; cp < 2; cp++) {
      int icol = ib + 32 * ch + cp * 16 + l15;
#pragma unroll
      for (int v = 0; v < 4; v++) {
        int row = rh * 64 + rb * 16 + quad * 4 + v;
        int pos = row0 + row;
        if (pos < Ne) {
          float g = acc[rb][2 * cp][v], u = acc[rb][2 * cp + 1][v];
          float a = g / (1.f + __expf(-g)) * u;
          a_buf[(size_t)(slot_base + pos) * I_DIM + icol] = f2bf(a);
        }
      }
    }
}

// ---- GEMM2: 128x128 tile, split-K (2 halves), double-buffered single-barrier
//      K-loop; gated bf16 partials into y_part[kh] ----
__global__ __launch_bounds__(256) void gemm2_kernel(
    const unsigned short* __restrict__ a_buf,    // [8192][2048] bf16
    const unsigned short* __restrict__ w_out_t,  // [E][1024][2048] bf16
    const int* __restrict__ counts, const int* __restrict__ base,
    const float* __restrict__ list_gate,
    unsigned short* __restrict__ y_part)         // [2][8192][1024] bf16
{
  int e = blockIdx.z >> 1, kh = blockIdx.z & 1;
  int Ne = counts[e];
  int row0 = blockIdx.x * 128;
  if (row0 >= Ne) return;
  int hb = blockIdx.y * 128;
  const unsigned short* W = w_out_t + (size_t)e * 1024 * 2048;
  int slot_base = base[e];
  int kbase = kh * 1024;
  unsigned short* yb = y_part + (size_t)kh * 8192 * 1024;

  __shared__ __align__(16) unsigned short As[2][128 * 32];
  __shared__ __align__(16) unsigned short Bs[2][128 * 32];
  __shared__ float gts[128];

  int tid = threadIdx.x;
  if (tid < 128) {
    int pos = row0 + tid;
    gts[tid] = list_gate[e * T_TOKENS + (pos < Ne ? pos : Ne - 1)];
  }

  int wv = tid >> 6, lane = tid & 63;
  const unsigned short* srcA[2];
  const unsigned short* srcB[2];
  int ldsOff[2];
#pragma unroll
  for (int d = 0; d < 2; d++) {
    int r = 32 * wv + 16 * d + (lane >> 2);
    int kg = (lane & 3) ^ SWZ(r);
    int pos = row0 + r;
    int slot = slot_base + (pos < Ne ? pos : Ne - 1);
    srcA[d] = a_buf + (size_t)slot * I_DIM + kbase + kg * 8;
    srcB[d] = W + (size_t)(hb + r) * I_DIM + kbase + kg * 8;
    ldsOff[d] = (32 * wv + 16 * d) * 32;
  }

  int rh = wv >> 1, ch = wv & 1;
  int l15 = lane & 15, quad = lane >> 4;

  f32x4 acc[4][4] = {};

  load16_lds(srcA[0], &As[0][ldsOff[0]]);
  load16_lds(srcA[1], &As[0][ldsOff[1]]);
  load16_lds(srcB[0], &Bs[0][ldsOff[0]]);
  load16_lds(srcB[1], &Bs[0][ldsOff[1]]);
  __syncthreads();

  int p = 0;
  for (int k0 = 0; k0 < 1024; k0 += 32) {
    int kn = k0 + 32;
    if (kn < 1024) {
      load16_lds(srcA[0] + kn, &As[1 - p][ldsOff[0]]);
      load16_lds(srcA[1] + kn, &As[1 - p][ldsOff[1]]);
      load16_lds(srcB[0] + kn, &Bs[1 - p][ldsOff[0]]);
      load16_lds(srcB[1] + kn, &Bs[1 - p][ldsOff[1]]);
    }
    bf16x8 af[4], bf[4];
#pragma unroll
    for (int rb = 0; rb < 4; rb++) {
      int row = rh * 64 + rb * 16 + l15;
      int kg = quad ^ SWZ(row);
      af[rb] = *(const bf16x8*)&As[p][row * 32 + kg * 8];
    }
#pragma unroll
    for (int cb = 0; cb < 4; cb++) {
      int brow = ch * 64 + cb * 16 + l15;
      int kg = quad ^ SWZ(brow);
      bf[cb] = *(const bf16x8*)&Bs[p][brow * 32 + kg * 8];
    }
#pragma unroll
    for (int rb = 0; rb < 4; rb++)
#pragma unroll
      for (int cb = 0; cb < 4; cb++)
        acc[rb][cb] = __builtin_amdgcn_mfma_f32_16x16x32_bf16(af[rb], bf[cb], acc[rb][cb], 0, 0, 0);
    __syncthreads();
    p ^= 1;
  }

#pragma unroll
  for (int rb = 0; rb < 4; rb++)
#pragma unroll
    for (int cb = 0; cb < 4; cb++) {
      int col = hb + ch * 64 + cb * 16 + l15;
#pragma unroll
      for (int v = 0; v < 4; v++) {
        int row = rh * 64 + rb * 16 + quad * 4 + v;
        int pos = row0 + row;
        if (pos < Ne)
          yb[(size_t)(slot_base + pos) * H_DIM + col] = f2bf(gts[row] * acc[rb][cb][v]);
      }
    }
}

// ---- combine: out[t] = sum over {2 experts} x {2 K-halves} ----
__global__ void combine_kernel(const unsigned short* __restrict__ y_part,
                               const int* __restrict__ tok_codes,
                               const int* __restrict__ base,
                               float* __restrict__ out) {
  int t = blockIdx.x;
  int c0 = tok_codes[2 * t], c1 = tok_codes[2 * t + 1];
  size_t s0 = (size_t)(base[c0 / T_TOKENS] + (c0 % T_TOKENS)) * H_DIM;
  size_t s1 = (size_t)(base[c1 / T_TOKENS] + (c1 % T_TOKENS)) * H_DIM;
  const size_t HALF = (size_t)8192 * 1024;
  int h = threadIdx.x * 4;
  ushort4 a0 = *(const ushort4*)&y_part[s0 + h];
  ushort4 a1 = *(const ushort4*)&y_part[HALF + s0 + h];
  ushort4 b0 = *(const ushort4*)&y_part[s1 + h];
  ushort4 b1 = *(const ushort4*)&y_part[HALF + s1 + h];
  float4 o;
  o.x = (bf2f(a0.x) + bf2f(a1.x)) + (bf2f(b0.x) + bf2f(b1.x));
  o.y = (bf2f(a0.y) + bf2f(a1.y)) + (bf2f(b0.y) + bf2f(b1.y));
  o.z = (bf2f(a0.z) + bf2f(a1.z)) + (bf2f(b0.z) + bf2f(b1.z));
  o.w = (bf2f(a0.w) + bf2f(a1.w)) + (bf2f(b0.w) + bf2f(b1.w));
  *(float4*)&out[(size_t)t * H_DIM + h] = o;
}

extern "C" void kernel_launch(void* const* d_in, const int* in_sizes, int n_in,
                              void* d_out, int out_size, void* d_ws, size_t ws_size,
                              hipStream_t stream) {
  const float* x     = (const float*)d_in[0];
  const float* Wg    = (const float*)d_in[1];
  const float* W_in  = (const float*)d_in[2];
  const float* W_out = (const float*)d_in[3];

  char* ws = (char*)d_ws;
  size_t off = 0;
  auto alloc = [&](size_t bytes) {
    char* p = ws + off;
    off += (bytes + 255) & ~(size_t)255;
    return p;
  };
  unsigned short* xb      = (unsigned short*)alloc((size_t)T_TOKENS * H_DIM * 2);
  unsigned short* w_in_t  = (unsigned short*)alloc((size_t)E_EXP * 2 * I_DIM * H_DIM * 2); // 67MB
  unsigned short* w_out_t = (unsigned short*)alloc((size_t)E_EXP * H_DIM * I_DIM * 2);
  unsigned short* a_buf   = (unsigned short*)alloc((size_t)2 * T_TOKENS * I_DIM * 2);
  int*   counts    = (int*)alloc(E_EXP * 4);
  int*   base      = (int*)alloc(E_EXP * 4);
  int*   list_tok  = (int*)alloc((size_t)E_EXP * T_TOKENS * 4);
  float* list_gate = (float*)alloc((size_t)E_EXP * T_TOKENS * 4);
  int*   tok_codes = (int*)alloc((size_t)2 * T_TOKENS * 4);
  if (off > ws_size) return;

  // y_part (2 x 16.8 MB = 33.6 MB) aliases w_in_t (67 MB, dead after gemm1)
  unsigned short* y_part = w_in_t;

  hipMemsetAsync(counts, 0, E_EXP * 4, stream);

  // W_in [E][1024][4096] -> [E][4096][1024]
  cast_transpose_kernel<<<dim3(4096 / 32, 1024 / 64, E_EXP), 256, 0, stream>>>(W_in, w_in_t, 1024, 4096);
  // W_out [E][2048][1024] -> [E][1024][2048]
  cast_transpose_kernel<<<dim3(1024 / 32, 2048 / 64, E_EXP), 256, 0, stream>>>(W_out, w_out_t, 2048, 1024);
  router_kernel<<<T_TOKENS, 64, 0, stream>>>(x, Wg, xb, counts, list_tok, list_gate, tok_codes);
  prefix_kernel<<<1, 1, 0, stream>>>(counts, base);
  gemm1_kernel<<<dim3(T_TOKENS / 128, I_DIM / 64, E_EXP), 256, 0, stream>>>(
      xb, w_in_t, counts, base, list_tok, a_buf);
  gemm2_kernel<<<dim3(T_TOKENS / 128, H_DIM / 128, E_EXP * 2), 256, 0, stream>>>(
      a_buf, w_out_t, counts, base, list_gate, y_part);
  combine_kernel<<<T_TOKENS, 256, 0, stream>>>(y_part, tok_codes, base, (float*)d_out);
}

// Round 5
// 443.515 us; speedup vs baseline: 2.0896x; 2.0896x over previous
//
#include <hip/hip_runtime.h>
#include <hip/hip_bf16.h>

// Problem constants (B=2,S=2048,H=1024,E=8,I=2048,topk=2)
#define T_TOKENS 4096
#define H_DIM    1024
#define E_EXP    8
#define I_DIM    2048

typedef short bf16x8 __attribute__((ext_vector_type(8)));
typedef float f32x4  __attribute__((ext_vector_type(4)));

// XOR swizzle of 16B k-group slots vs LDS row (row stride 64B)
#define SWZ(r) (((r) >> 1) & 3)

__device__ inline unsigned short f2bf(float f) {
  union { __hip_bfloat16 h; unsigned short u; } c;
  c.h = __float2bfloat16(f);
  return c.u;
}
__device__ inline float bf2f(unsigned short u) {
  union { unsigned int i; float f; } c;
  c.i = (unsigned int)u << 16;
  return c.f;
}

// async global->LDS DMA, 16 B/lane, dest = wave-uniform base + lane*16
__device__ inline void load16_lds(const void* g, void* l) {
  __builtin_amdgcn_global_load_lds(
      (const __attribute__((address_space(1))) unsigned int*)g,
      (__attribute__((address_space(3))) unsigned int*)l, 16, 0, 0);
}

// ---- transpose one 64k x 64n tile: [K][N] f32 -> [N][K] bf16 ----
__device__ inline void do_transpose(const float* __restrict__ src,
                                    unsigned short* __restrict__ dst,
                                    int K, int N, int kb, int nb,
                                    float (*tile)[65], int tid) {
  int k0 = kb * 64, n0 = nb * 64;
#pragma unroll
  for (int i = 0; i < 4; i++) {
    int row = (tid >> 4) + i * 16;
    int col4 = (tid & 15) * 4;
    float4 v = *(const float4*)(src + (size_t)(k0 + row) * N + n0 + col4);
    tile[row][col4] = v.x; tile[row][col4 + 1] = v.y;
    tile[row][col4 + 2] = v.z; tile[row][col4 + 3] = v.w;
  }
  __syncthreads();
#pragma unroll
  for (int s = 0; s < 2; s++) {
    int n = s * 32 + (tid >> 3), kg = tid & 7;
    __align__(16) unsigned short o[8];
#pragma unroll
    for (int j = 0; j < 8; j++) o[j] = f2bf(tile[kg * 8 + j][n]);
    *(uint4*)&dst[(size_t)(n0 + n) * K + k0 + kg * 8] = *(uint4*)o;
  }
}

// ---- router for one token (one wave): fp32 logits, top-2, softmax gates ----
__device__ inline void do_router(const float* __restrict__ x, const float* __restrict__ Wg,
                                 unsigned short* __restrict__ xb, int t, int lane,
                                 int2* __restrict__ te, float2* __restrict__ tg) {
  float acc[8];
#pragma unroll
  for (int e = 0; e < 8; e++) acc[e] = 0.f;
  const float* xr = x + (size_t)t * H_DIM;
  unsigned short* xbr = xb + (size_t)t * H_DIM;
  for (int h = lane; h < H_DIM; h += 64) {
    float xv = xr[h];
    xbr[h] = f2bf(xv);
    const float4* w = (const float4*)(Wg + (size_t)h * 8);
    float4 w0 = w[0], w1 = w[1];
    acc[0] += xv * w0.x; acc[1] += xv * w0.y; acc[2] += xv * w0.z; acc[3] += xv * w0.w;
    acc[4] += xv * w1.x; acc[5] += xv * w1.y; acc[6] += xv * w1.z; acc[7] += xv * w1.w;
  }
#pragma unroll
  for (int off = 32; off > 0; off >>= 1)
#pragma unroll
    for (int e = 0; e < 8; e++) acc[e] += __shfl_xor(acc[e], off, 64);
  if (lane == 0) {
    int e1 = 0; float l1 = acc[0];
    for (int e = 1; e < 8; e++) if (acc[e] > l1) { l1 = acc[e]; e1 = e; }
    int e2 = -1; float l2 = -1e30f;
    for (int e = 0; e < 8; e++) if (e != e1 && acc[e] > l2) { l2 = acc[e]; e2 = e; }
    float g1 = 1.f / (1.f + expf(l2 - l1));   // softmax over [l1,l2], l1>=l2
    te[t] = make_int2(e1, e2);
    tg[t] = make_float2(g1, 1.f - g1);
  }
}

// ---- prep: W_in transpose (blocks 0..8191), W_out transpose (8192..12287),
//      router+cast (12288..13311, 4 tokens/block) — one launch ----
__global__ __launch_bounds__(256) void prep_kernel(
    const float* __restrict__ W_in, const float* __restrict__ W_out,
    const float* __restrict__ x, const float* __restrict__ Wg,
    unsigned short* __restrict__ w_in_t, unsigned short* __restrict__ w_out_t,
    unsigned short* __restrict__ xb, int2* __restrict__ te, float2* __restrict__ tg) {
  __shared__ float tile[64][65];
  int id = blockIdx.x, tid = threadIdx.x;
  if (id < 8192) {                       // W_in [E][1024][4096] -> [E][4096][1024]
    int e = id >> 10, r = id & 1023, nb = r & 63, kb = r >> 6;
    do_transpose(W_in + (size_t)e * 1024 * 4096, w_in_t + (size_t)e * 4096 * 1024,
                 1024, 4096, kb, nb, tile, tid);
  } else if (id < 12288) {               // W_out [E][2048][1024] -> [E][1024][2048]
    int t2 = id - 8192;
    int e = t2 >> 9, r = t2 & 511, nb = r & 15, kb = r >> 4;
    do_transpose(W_out + (size_t)e * 2048 * 1024, w_out_t + (size_t)e * 1024 * 2048,
                 2048, 1024, kb, nb, tile, tid);
  } else {                               // router, 4 tokens per block (1/wave)
    int t = (id - 12288) * 4 + (tid >> 6);
    do_router(x, Wg, xb, t, tid & 63, te, tg);
  }
}

// ---- schedule: bin 8192 (token,expert) picks -> lists, counts, base, codes ----
__global__ __launch_bounds__(256) void schedule_kernel(
    const int2* __restrict__ te, const float2* __restrict__ tg,
    int* __restrict__ counts, int* __restrict__ base,
    int* __restrict__ list_tok, float* __restrict__ list_gate,
    int* __restrict__ tok_codes) {
  __shared__ int cnt[8];
  int tid = threadIdx.x;
  if (tid < 8) cnt[tid] = 0;
  __syncthreads();
  for (int t = tid; t < T_TOKENS; t += 256) {
    int2 e = te[t]; float2 g = tg[t];
    int p1 = atomicAdd(&cnt[e.x], 1);
    list_tok[e.x * T_TOKENS + p1] = t; list_gate[e.x * T_TOKENS + p1] = g.x;
    tok_codes[2 * t] = e.x * T_TOKENS + p1;
    int p2 = atomicAdd(&cnt[e.y], 1);
    list_tok[e.y * T_TOKENS + p2] = t; list_gate[e.y * T_TOKENS + p2] = g.y;
    tok_codes[2 * t + 1] = e.y * T_TOKENS + p2;
  }
  __syncthreads();
  if (tid == 0) {
    int s = 0;
    for (int e = 0; e < 8; e++) { base[e] = s; counts[e] = cnt[e]; s += cnt[e]; }
  }
}

// ---- GEMM1: 128 tokens x 64 i-cols (g/u interleaved 128-row B-tile), m97-style
//      single-buffer K-loop, DMA staging, swizzled LDS, fused silu(g)*u ----
__global__ __launch_bounds__(256) void gemm1_kernel(
    const unsigned short* __restrict__ xb,      // [T][1024] bf16
    const unsigned short* __restrict__ w_in_t,  // [E][4096][1024] bf16
    const int* __restrict__ counts, const int* __restrict__ base,
    const int* __restrict__ list_tok,
    unsigned short* __restrict__ a_buf)         // [8192][2048] bf16
{
  int e = blockIdx.z;
  int Ne = counts[e];
  int row0 = blockIdx.y * 128;
  if (row0 >= Ne) return;
  int ib = blockIdx.x * 64;                     // x = i-col fastest (L2 A-tile sharing)
  const unsigned short* W = w_in_t + (size_t)e * 4096 * 1024;
  int slot_base = base[e];

  __shared__ __align__(16) unsigned short As[128 * 32];   // 8 KB
  __shared__ __align__(16) unsigned short Bs[128 * 32];   // 8 KB
  __shared__ int toks[128];

  int tid = threadIdx.x;
  if (tid < 128) {
    int pos = row0 + tid;
    toks[tid] = list_tok[e * T_TOKENS + (pos < Ne ? pos : 0)];
  }
  __syncthreads();

  int wv = tid >> 6, lane = tid & 63;

  const unsigned short* srcA[2];
  const unsigned short* srcB[2];
  unsigned short* ldsA[2];
  unsigned short* ldsB[2];
#pragma unroll
  for (int d = 0; d < 2; d++) {
    int r = 32 * wv + 16 * d + (lane >> 2);        // tile-local row 0..127
    int kg = (lane & 3) ^ SWZ(r);
    srcA[d] = xb + (size_t)toks[r] * H_DIM + kg * 8;
    // B-tile row r -> W row: c=r>>6 (wave col-half), q=(r>>4)&3 (g/u alt), rr=r&15
    int c = r >> 6, q = (r >> 4) & 3, rr = r & 15;
    int wrow = (q & 1) * 2048 + ib + 32 * c + (q >> 1) * 16 + rr;
    srcB[d] = W + (size_t)wrow * H_DIM + kg * 8;
    ldsA[d] = As + (32 * wv + 16 * d) * 32;
    ldsB[d] = Bs + (32 * wv + 16 * d) * 32;
  }

  int rh = wv >> 1, ch = wv & 1;
  int l15 = lane & 15, quad = lane >> 4;

  f32x4 acc[4][4] = {};

  for (int k0 = 0; k0 < H_DIM; k0 += 32) {
    load16_lds(srcA[0] + k0, ldsA[0]);
    load16_lds(srcA[1] + k0, ldsA[1]);
    load16_lds(srcB[0] + k0, ldsB[0]);
    load16_lds(srcB[1] + k0, ldsB[1]);
    __syncthreads();

    bf16x8 af[4], bf[4];
#pragma unroll
    for (int rb = 0; rb < 4; rb++) {
      int row = rh * 64 + rb * 16 + l15;
      int kg = quad ^ SWZ(row);
      af[rb] = *(const bf16x8*)&As[row * 32 + kg * 8];
    }
#pragma unroll
    for (int cb = 0; cb < 4; cb++) {
      int brow = ch * 64 + cb * 16 + l15;
      int kg = quad ^ SWZ(brow);
      bf[cb] = *(const bf16x8*)&Bs[brow * 32 + kg * 8];
    }
#pragma unroll
    for (int rb = 0; rb < 4; rb++)
#pragma unroll
      for (int cb = 0; cb < 4; cb++)
        acc[rb][cb] = __builtin_amdgcn_mfma_f32_16x16x32_bf16(af[rb], bf[cb], acc[rb][cb], 0, 0, 0);
    __syncthreads();
  }

  // epilogue: B col-blocks alternate g,u,g,u (16-wide). Pair (2cp, 2cp+1).
#pragma unroll
  for (int rb = 0; rb < 4; rb++)
#pragma unroll
    for (int cp = 0; cp < 2; cp++) {
      int icol = ib + 32 * ch + cp * 16 + l15;
#pragma unroll
      for (int v = 0; v < 4; v++) {
        int row = rh * 64 + rb * 16 + quad * 4 + v;
        int pos = row0 + row;
        if (pos < Ne) {
          float g = acc[rb][2 * cp][v], u = acc[rb][2 * cp + 1][v];
          float a = g / (1.f + __expf(-g)) * u;
          a_buf[(size_t)(slot_base + pos) * I_DIM + icol] = f2bf(a);
        }
      }
    }
}

// ---- GEMM2: m97 structure 128x128, gated bf16 y into y_buf (no atomics) ----
__global__ __launch_bounds__(256) void gemm2_kernel(
    const unsigned short* __restrict__ a_buf,    // [8192][2048] bf16
    const unsigned short* __restrict__ w_out_t,  // [E][1024][2048] bf16
    const int* __restrict__ counts, const int* __restrict__ base,
    const float* __restrict__ list_gate,
    unsigned short* __restrict__ y_buf)          // [8192][1024] bf16
{
  int e = blockIdx.z;
  int Ne = counts[e];
  int row0 = blockIdx.y * 128;
  if (row0 >= Ne) return;
  int hb = blockIdx.x * 128;
  const unsigned short* W = w_out_t + (size_t)e * 1024 * 2048;
  int slot_base = base[e];

  __shared__ __align__(16) unsigned short As[128 * 32];   // 8 KB
  __shared__ __align__(16) unsigned short Bs[128 * 32];   // 8 KB
  __shared__ float gts[128];

  int tid = threadIdx.x;
  if (tid < 128) {
    int pos = row0 + tid;
    gts[tid] = list_gate[e * T_TOKENS + (pos < Ne ? pos : Ne - 1)];
  }

  int wv = tid >> 6, lane = tid & 63;
  const unsigned short* srcA[2];
  const unsigned short* srcB[2];
  unsigned short* ldsA[2];
  unsigned short* ldsB[2];
#pragma unroll
  for (int d = 0; d < 2; d++) {
    int r = 32 * wv + 16 * d + (lane >> 2);
    int kg = (lane & 3) ^ SWZ(r);
    int pos = row0 + r;
    int slot = slot_base + (pos < Ne ? pos : Ne - 1);
    srcA[d] = a_buf + (size_t)slot * I_DIM + kg * 8;
    srcB[d] = W + (size_t)(hb + r) * I_DIM + kg * 8;
    ldsA[d] = As + (32 * wv + 16 * d) * 32;
    ldsB[d] = Bs + (32 * wv + 16 * d) * 32;
  }

  int rh = wv >> 1, ch = wv & 1;
  int l15 = lane & 15, quad = lane >> 4;

  f32x4 acc[4][4] = {};

  for (int k0 = 0; k0 < I_DIM; k0 += 32) {
    load16_lds(srcA[0] + k0, ldsA[0]);
    load16_lds(srcA[1] + k0, ldsA[1]);
    load16_lds(srcB[0] + k0, ldsB[0]);
    load16_lds(srcB[1] + k0, ldsB[1]);
    __syncthreads();

    bf16x8 af[4], bf[4];
#pragma unroll
    for (int rb = 0; rb < 4; rb++) {
      int row = rh * 64 + rb * 16 + l15;
      int kg = quad ^ SWZ(row);
      af[rb] = *(const bf16x8*)&As[row * 32 + kg * 8];
    }
#pragma unroll
    for (int cb = 0; cb < 4; cb++) {
      int brow = ch * 64 + cb * 16 + l15;
      int kg = quad ^ SWZ(brow);
      bf[cb] = *(const bf16x8*)&Bs[brow * 32 + kg * 8];
    }
#pragma unroll
    for (int rb = 0; rb < 4; rb++)
#pragma unroll
      for (int cb = 0; cb < 4; cb++)
        acc[rb][cb] = __builtin_amdgcn_mfma_f32_16x16x32_bf16(af[rb], bf[cb], acc[rb][cb], 0, 0, 0);
    __syncthreads();
  }

#pragma unroll
  for (int rb = 0; rb < 4; rb++)
#pragma unroll
    for (int cb = 0; cb < 4; cb++) {
      int col = hb + ch * 64 + cb * 16 + l15;
#pragma unroll
      for (int v = 0; v < 4; v++) {
        int row = rh * 64 + rb * 16 + quad * 4 + v;
        int pos = row0 + row;
        if (pos < Ne)
          y_buf[(size_t)(slot_base + pos) * H_DIM + col] = f2bf(gts[row] * acc[rb][cb][v]);
      }
    }
}

// ---- combine: out[t] = y[slot1] + y[slot2] (gates pre-applied) ----
__global__ void combine_kernel(const unsigned short* __restrict__ y_buf,
                               const int* __restrict__ tok_codes,
                               const int* __restrict__ base,
                               float* __restrict__ out) {
  int t = blockIdx.x;
  int c0 = tok_codes[2 * t], c1 = tok_codes[2 * t + 1];
  int s0 = base[c0 / T_TOKENS] + (c0 % T_TOKENS);
  int s1 = base[c1 / T_TOKENS] + (c1 % T_TOKENS);
  int h = threadIdx.x * 4;
  ushort4 a = *(const ushort4*)&y_buf[(size_t)s0 * H_DIM + h];
  ushort4 b = *(const ushort4*)&y_buf[(size_t)s1 * H_DIM + h];
  float4 o;
  o.x = bf2f(a.x) + bf2f(b.x);
  o.y = bf2f(a.y) + bf2f(b.y);
  o.z = bf2f(a.z) + bf2f(b.z);
  o.w = bf2f(a.w) + bf2f(b.w);
  *(float4*)&out[(size_t)t * H_DIM + h] = o;
}

extern "C" void kernel_launch(void* const* d_in, const int* in_sizes, int n_in,
                              void* d_out, int out_size, void* d_ws, size_t ws_size,
                              hipStream_t stream) {
  const float* x     = (const float*)d_in[0];
  const float* Wg    = (const float*)d_in[1];
  const float* W_in  = (const float*)d_in[2];
  const float* W_out = (const float*)d_in[3];

  char* ws = (char*)d_ws;
  size_t off = 0;
  auto alloc = [&](size_t bytes) {
    char* p = ws + off;
    off += (bytes + 255) & ~(size_t)255;
    return p;
  };
  unsigned short* xb      = (unsigned short*)alloc((size_t)T_TOKENS * H_DIM * 2);
  unsigned short* w_in_t  = (unsigned short*)alloc((size_t)E_EXP * 2 * I_DIM * H_DIM * 2); // 67MB
  unsigned short* w_out_t = (unsigned short*)alloc((size_t)E_EXP * H_DIM * I_DIM * 2);
  unsigned short* a_buf   = (unsigned short*)alloc((size_t)2 * T_TOKENS * I_DIM * 2);
  int*   counts    = (int*)alloc(E_EXP * 4);
  int*   base      = (int*)alloc(E_EXP * 4);
  int*   list_tok  = (int*)alloc((size_t)E_EXP * T_TOKENS * 4);
  float* list_gate = (float*)alloc((size_t)E_EXP * T_TOKENS * 4);
  int*   tok_codes = (int*)alloc((size_t)2 * T_TOKENS * 4);
  int2*  te        = (int2*)alloc((size_t)T_TOKENS * 8);
  float2* tg       = (float2*)alloc((size_t)T_TOKENS * 8);
  if (off > ws_size) return;

  // y_buf (16.8 MB) aliases w_in_t (67 MB, dead after gemm1)
  unsigned short* y_buf = w_in_t;

  prep_kernel<<<13312, 256, 0, stream>>>(W_in, W_out, x, Wg, w_in_t, w_out_t, xb, te, tg);
  schedule_kernel<<<1, 256, 0, stream>>>(te, tg, counts, base, list_tok, list_gate, tok_codes);
  gemm1_kernel<<<dim3(I_DIM / 64, T_TOKENS / 128, E_EXP), 256, 0, stream>>>(
      xb, w_in_t, counts, base, list_tok, a_buf);
  gemm2_kernel<<<dim3(H_DIM / 128, T_TOKENS / 128, E_EXP), 256, 0, stream>>>(
      a_buf, w_out_t, counts, base, list_gate, y_buf);
  combine_kernel<<<T_TOKENS, 256, 0, stream>>>(y_buf, tok_codes, base, (float*)d_out);
}